// Round 11
// baseline (295.731 us; speedup 1.0000x reference)
//
#include <hip/hip_runtime.h>
#include <math.h>

#define TILE 128

typedef __attribute__((ext_vector_type(8))) short short8v;
typedef __attribute__((ext_vector_type(4))) float f32x4;

// constants: 1/T and 1/(T*ln2)
#define INV_T 14.285714285714286f
#define K2C   20.60992915f
#define TIME_THR 5000000

__device__ __forceinline__ unsigned pack_bf16x2(float lo, float hi) {
  unsigned a = __float_as_uint(lo);
  unsigned b = __float_as_uint(hi);
  a = (a + 0x7FFFu + ((a >> 16) & 1u)) >> 16;
  b = (b + 0x7FFFu + ((b >> 16) & 1u)) & 0xFFFF0000u;
  return b | a;
}

__device__ __forceinline__ void gl_lds16(const void* g, void* l) {
  __builtin_amdgcn_global_load_lds(
      (const __attribute__((address_space(1))) unsigned int*)g,
      (__attribute__((address_space(3))) unsigned int*)l, 16, 0, 0);
}

// ============ 128x128 single-buffer high-occupancy kernel ============
// 4 waves (2x2), per-wave 64x64 (acc[4][4] 16x16 frags). LDS = 32KB
// ([128][64] x2, proven conflict-free XOR swizzle) -> 4 blocks/CU
// (16 waves) vs R7's 2. Step: vmcnt(0)+bar -> 16 ds_read -> lgkm(0)+bar
// -> stage next INTO SAME buffers -> MFMA under staging latency.
// Latency hiding comes from TLP (16 waves/CU), not double-buffering.
__global__ __launch_bounds__(256, 4) void gram128s(
    const unsigned short* __restrict__ descb, const int* __restrict__ seq,
    const int* __restrict__ tmid, float* __restrict__ p_se,
    float* __restrict__ p_ps, float* __restrict__ p_pc, int B, int D, int NB) {
  __shared__ __align__(16) unsigned short lA[TILE][64];
  __shared__ __align__(16) unsigned short lB[TILE][64];

  // ---- triangular block decode + XCD swizzle ----
  const int T = NB * (NB + 1) / 2;
  int t = blockIdx.x;
  if ((T & 7) == 0) t = (t & 7) * (T >> 3) + (t >> 3);
  float fn = (float)NB + 0.5f;
  int r = (int)(fn - sqrtf(fmaxf(fn * fn - 2.0f * (float)t, 0.0f)));
  if (r < 0) r = 0;
  if (r > NB - 1) r = NB - 1;
  auto Sf = [NB](int rr) { return rr * NB - ((rr * (rr - 1)) >> 1); };
  while (r > 0 && Sf(r) > t) --r;
  while (r < NB - 1 && Sf(r + 1) <= t) ++r;
  const int rb = r;
  const int cb = rb + (t - Sf(rb));
  const bool upper = (cb != rb);
  const int row0 = rb * TILE;
  const int col0 = cb * TILE;

  const int tid = threadIdx.x;
  const int l = tid & 63;
  const int w = tid >> 6;          // 0..3 (2x2)
  const int wrow = (w >> 1) << 6;  // 0 or 64
  const int wcol = (w & 1) << 6;   // 0 or 64
  const int lr = l & 15;
  const int kg = l >> 4;

  f32x4 acc[4][4];
#pragma unroll
  for (int m = 0; m < 4; ++m)
#pragma unroll
    for (int n = 0; n < 4; ++n) acc[m][n] = (f32x4){0.f, 0.f, 0.f, 0.f};

  // staging geometry (R7-proven): granule = q*256+tid covers row
  // rg = q*32 + (tid>>3), slot = tid&7; linear LDS dest (rule #21),
  // source chunk pre-swizzled c8 = slot ^ (rg&7).
  const int c8 = (l & 7) ^ ((l >> 3) & 7);
  const int rbase = (w << 3) + (l >> 3);
  const int NT = D >> 6;

  auto stage = [&](int tt) {
    const int k0 = tt << 6;
#pragma unroll
    for (int q = 0; q < 4; ++q) {
      const int rg = (q << 5) + rbase;
      const int ldsoff = (q << 12) + (w << 10);
      gl_lds16(descb + (size_t)(row0 + rg) * D + k0 + (c8 << 3),
               (char*)&lA[0][0] + ldsoff);
      gl_lds16(descb + (size_t)(col0 + rg) * D + k0 + (c8 << 3),
               (char*)&lB[0][0] + ldsoff);
    }
  };

  stage(0);
  for (int ts = 0; ts < NT; ++ts) {
    asm volatile("s_waitcnt vmcnt(0)" ::: "memory");  // panel ts landed
    __builtin_amdgcn_sched_barrier(0);
    __builtin_amdgcn_s_barrier();  // visible to all waves
    __builtin_amdgcn_sched_barrier(0);

    short8v af[2][4], bf[2][4];
#pragma unroll
    for (int kk = 0; kk < 2; ++kk) {
#pragma unroll
      for (int m = 0; m < 4; ++m) {
        const int rowa = wrow + (m << 4) + lr;
        const int ch = ((kk << 2) + kg) ^ (rowa & 7);
        af[kk][m] = *reinterpret_cast<const short8v*>(&lA[rowa][ch << 3]);
      }
#pragma unroll
      for (int n = 0; n < 4; ++n) {
        const int rowb = wcol + (n << 4) + lr;
        const int ch = ((kk << 2) + kg) ^ (rowb & 7);
        bf[kk][n] = *reinterpret_cast<const short8v*>(&lB[rowb][ch << 3]);
      }
    }
    __builtin_amdgcn_sched_barrier(0);
    asm volatile("s_waitcnt lgkmcnt(0)" ::: "memory");  // frags in regs
    __builtin_amdgcn_sched_barrier(0);
    __builtin_amdgcn_s_barrier();  // all waves done reading -> overwrite ok
    __builtin_amdgcn_sched_barrier(0);
    if (ts + 1 < NT) stage(ts + 1);  // async refill under MFMA
    __builtin_amdgcn_sched_barrier(0);
    __builtin_amdgcn_s_setprio(1);
#pragma unroll
    for (int kk = 0; kk < 2; ++kk)
#pragma unroll
      for (int m = 0; m < 4; ++m)
#pragma unroll
        for (int n = 0; n < 4; ++n)
          acc[m][n] = __builtin_amdgcn_mfma_f32_16x16x32_bf16(
              af[kk][m], bf[kk][n], acc[m][n], 0, 0, 0);
    __builtin_amdgcn_s_setprio(0);
    __builtin_amdgcn_sched_barrier(0);
  }
  __syncthreads();  // drain before LDS reuse

  // ---- epilogue: atomic-free partials (proven R5-R7 structure) ----
  float* rowred = (float*)&lA[0][0];  // [2][TILE][3]
  float* colred = (float*)&lB[0][0];  // [2][TILE][3]

  int cseq[4], ctim[4], gcol[4];
#pragma unroll
  for (int n = 0; n < 4; ++n) {
    const int cl = wcol + (n << 4) + lr;
    gcol[n] = col0 + cl;
    cseq[n] = seq[gcol[n]];
    ctim[n] = tmid[gcol[n]];
  }
  float colse[4] = {0.f, 0.f, 0.f, 0.f};
  float colpd[4] = {0.f, 0.f, 0.f, 0.f};
  float colpc[4] = {0.f, 0.f, 0.f, 0.f};

#pragma unroll
  for (int m = 0; m < 4; ++m) {
#pragma unroll
    for (int reg = 0; reg < 4; ++reg) {
      const int rl = wrow + (m << 4) + (kg << 2) + reg;  // row within tile
      const int growg = row0 + rl;
      const int rs = seq[growg];
      const int rt = tmid[growg];
      float se = 0.f, pd = 0.f, pcnt = 0.f;
#pragma unroll
      for (int n = 0; n < 4; ++n) {
        const float dot = acc[m][n][reg];
        const float e = exp2f(fmaf(dot, K2C, -K2C));
        const bool nd = (growg != gcol[n]);
        int dt = rt - ctim[n];
        dt = dt < 0 ? -dt : dt;
        const bool pos = nd && (rs == cseq[n]) && (dt < TIME_THR);
        const float ev = nd ? e : 0.f;
        const float dv = pos ? dot : 0.f;
        const float cv = pos ? 1.f : 0.f;
        se += ev;
        pd += dv;
        pcnt += cv;
        colse[n] += ev;
        colpd[n] += dv;
        colpc[n] += cv;
      }
#pragma unroll
      for (int s = 1; s < 16; s <<= 1) {
        se += __shfl_xor(se, s);
        pd += __shfl_xor(pd, s);
        pcnt += __shfl_xor(pcnt, s);
      }
      if (lr == 0) {
        const int half = wcol >> 6;
        float* rr3 = rowred + ((size_t)(half * TILE + rl)) * 3;
        rr3[0] = se;
        rr3[1] = pd;
        rr3[2] = pcnt;
      }
    }
  }
  if (upper) {
#pragma unroll
    for (int n = 0; n < 4; ++n) {
      float cs = colse[n], cp = colpd[n], cc = colpc[n];
      cs += __shfl_xor(cs, 16);
      cp += __shfl_xor(cp, 16);
      cc += __shfl_xor(cc, 16);
      cs += __shfl_xor(cs, 32);
      cp += __shfl_xor(cp, 32);
      cc += __shfl_xor(cc, 32);
      if (kg == 0) {
        const int half = wrow >> 6;
        const int cl = wcol + (n << 4) + lr;
        float* cr3 = colred + ((size_t)(half * TILE + cl)) * 3;
        cr3[0] = cs;
        cr3[1] = cp;
        cr3[2] = cc;
      }
    }
  }
  __syncthreads();

  if (tid < TILE) {
    const int row = tid;
    const float se = rowred[(size_t)row * 3 + 0] + rowred[(size_t)(TILE + row) * 3 + 0];
    const float pd = rowred[(size_t)row * 3 + 1] + rowred[(size_t)(TILE + row) * 3 + 1];
    const float pc = rowred[(size_t)row * 3 + 2] + rowred[(size_t)(TILE + row) * 3 + 2];
    const size_t o = (size_t)cb * B + row0 + row;  // slot-major, coalesced
    p_se[o] = se;
    p_ps[o] = pd * INV_T;
    p_pc[o] = pc;
  } else if (upper && tid < 2 * TILE) {
    const int col = tid - TILE;
    const float se = colred[(size_t)col * 3 + 0] + colred[(size_t)(TILE + col) * 3 + 0];
    const float pd = colred[(size_t)col * 3 + 1] + colred[(size_t)(TILE + col) * 3 + 1];
    const float pc = colred[(size_t)col * 3 + 2] + colred[(size_t)(TILE + col) * 3 + 2];
    const size_t o = (size_t)rb * B + col0 + col;  // slot-major, coalesced
    p_se[o] = se;
    p_ps[o] = pd * INV_T;
    p_pc[o] = pc;
  }
}

// ===================== 128x128 fallback (atomic epilogue) =====================
template <int MODE>
__device__ __forceinline__ void infonce_body(
    const float* __restrict__ desc, const unsigned short* __restrict__ descb,
    const int* __restrict__ seq, const int* __restrict__ tmid,
    float* __restrict__ p_se, float* __restrict__ p_ps,
    float* __restrict__ p_pc, int B, int D, int NB) {
  __shared__ __align__(16) unsigned short lA[2][128][64];
  __shared__ __align__(16) unsigned short lB[2][128][64];
  __shared__ int mseq_r[128], mtim_r[128], mseq_c[128], mtim_c[128];

  const int T = NB * (NB + 1) / 2;
  int t = blockIdx.x;
  if ((T & 7) == 0) t = (t & 7) * (T >> 3) + (t >> 3);
  float fn = (float)NB + 0.5f;
  int r = (int)(fn - sqrtf(fmaxf(fn * fn - 2.0f * (float)t, 0.0f)));
  if (r < 0) r = 0;
  if (r > NB - 1) r = NB - 1;
  auto Sf = [NB](int rr) { return rr * NB - ((rr * (rr - 1)) >> 1); };
  while (r > 0 && Sf(r) > t) --r;
  while (r < NB - 1 && Sf(r + 1) <= t) ++r;
  const int rb = r;
  const int cb = rb + (t - Sf(rb));
  const bool upper = (cb != rb);
  const int row0 = rb * 128;
  const int col0 = cb * 128;

  const int tid = threadIdx.x;
  const int l = tid & 63;
  const int w = tid >> 6;
  const int wrow = (w >> 1) << 6;
  const int wcol = (w & 1) << 6;
  const int lr = l & 15;
  const int kg = l >> 4;

  if (tid < 128) {
    mseq_r[tid] = seq[row0 + tid];
    mtim_r[tid] = tmid[row0 + tid];
    mseq_c[tid] = seq[col0 + tid];
    mtim_c[tid] = tmid[col0 + tid];
  }

  f32x4 acc[4][4];
#pragma unroll
  for (int m = 0; m < 4; ++m)
#pragma unroll
    for (int n = 0; n < 4; ++n) acc[m][n] = (f32x4){0.f, 0.f, 0.f, 0.f};

  const int c8 = (l & 7) ^ ((l >> 3) & 7);
  const int rbase = (w << 3) + (l >> 3);
  const int sr = tid >> 3;
  const int sc = tid & 7;
  const int NT = D >> 6;

  if (MODE >= 1) {
    auto stageA = [&](int tt) {
      const int bu = tt & 1;
      const int k0 = tt << 6;
#pragma unroll
      for (int q = 0; q < 4; ++q) {
        const int rg = (q << 5) + rbase;
        gl_lds16(descb + (size_t)(row0 + rg) * D + k0 + (c8 << 3),
                 (char*)&lA[bu][0][0] + (q << 12) + (w << 10));
      }
    };
    auto stageB = [&](int tt) {
      const int bu = tt & 1;
      const int k0 = tt << 6;
#pragma unroll
      for (int q = 0; q < 4; ++q) {
        const int rg = (q << 5) + rbase;
        gl_lds16(descb + (size_t)(col0 + rg) * D + k0 + (c8 << 3),
                 (char*)&lB[bu][0][0] + (q << 12) + (w << 10));
      }
    };
    __builtin_amdgcn_sched_barrier(0);
    stageA(0);
    stageB(0);
    __builtin_amdgcn_sched_barrier(0);
    for (int ts = 0; ts < NT; ++ts) {
      const int bu = ts & 1;
      if (ts + 1 < NT) {
        stageA(ts + 1);
        __builtin_amdgcn_sched_barrier(0);
        asm volatile("s_waitcnt vmcnt(4)" ::: "memory");
      } else {
        asm volatile("s_waitcnt vmcnt(0)" ::: "memory");
      }
      __builtin_amdgcn_sched_barrier(0);
      __builtin_amdgcn_s_barrier();
      __builtin_amdgcn_sched_barrier(0);
      short8v af[2][4], bf[2][4];
#pragma unroll
      for (int kk = 0; kk < 2; ++kk) {
#pragma unroll
        for (int m = 0; m < 4; ++m) {
          const int rowa = wrow + (m << 4) + lr;
          const int ch = ((kk << 2) + kg) ^ (rowa & 7);
          af[kk][m] = *reinterpret_cast<const short8v*>(&lA[bu][rowa][ch << 3]);
        }
#pragma unroll
        for (int n = 0; n < 4; ++n) {
          const int rowb = wcol + (n << 4) + lr;
          const int ch = ((kk << 2) + kg) ^ (rowb & 7);
          bf[kk][n] = *reinterpret_cast<const short8v*>(&lB[bu][rowb][ch << 3]);
        }
      }
      __builtin_amdgcn_sched_barrier(0);
      if (ts + 1 < NT) stageB(ts + 1);
      __builtin_amdgcn_sched_barrier(0);
      asm volatile("s_waitcnt lgkmcnt(0)" ::: "memory");
      __builtin_amdgcn_sched_barrier(0);
      __builtin_amdgcn_s_setprio(1);
#pragma unroll
      for (int kk = 0; kk < 2; ++kk)
#pragma unroll
        for (int m = 0; m < 4; ++m)
#pragma unroll
          for (int n = 0; n < 4; ++n)
            acc[m][n] = __builtin_amdgcn_mfma_f32_16x16x32_bf16(
                af[kk][m], bf[kk][n], acc[m][n], 0, 0, 0);
      __builtin_amdgcn_s_setprio(0);
      __builtin_amdgcn_sched_barrier(0);
      __builtin_amdgcn_s_barrier();
    }
    __syncthreads();
  } else {
    for (int k0 = 0; k0 < D; k0 += 64) {
      __syncthreads();
#pragma unroll
      for (int p = 0; p < 4; ++p) {
        const int rr = (p << 5) + sr;
        const float* gA = desc + (size_t)(row0 + rr) * D + k0 + (sc << 3);
        const float4 fa0 = *reinterpret_cast<const float4*>(gA);
        const float4 fa1 = *reinterpret_cast<const float4*>(gA + 4);
        const float* gB = desc + (size_t)(col0 + rr) * D + k0 + (sc << 3);
        const float4 fb0 = *reinterpret_cast<const float4*>(gB);
        const float4 fb1 = *reinterpret_cast<const float4*>(gB + 4);
        uint4 wa, wb;
        wa.x = pack_bf16x2(fa0.x, fa0.y);
        wa.y = pack_bf16x2(fa0.z, fa0.w);
        wa.z = pack_bf16x2(fa1.x, fa1.y);
        wa.w = pack_bf16x2(fa1.z, fa1.w);
        wb.x = pack_bf16x2(fb0.x, fb0.y);
        wb.y = pack_bf16x2(fb0.z, fb0.w);
        wb.z = pack_bf16x2(fb1.x, fb1.y);
        wb.w = pack_bf16x2(fb1.z, fb1.w);
        const int dst = (sc ^ (rr & 7)) << 3;
        *reinterpret_cast<uint4*>(&lA[0][rr][dst]) = wa;
        *reinterpret_cast<uint4*>(&lB[0][rr][dst]) = wb;
      }
      __syncthreads();
#pragma unroll
      for (int kk = 0; kk < 2; ++kk) {
        short8v af[4], bf[4];
#pragma unroll
        for (int m = 0; m < 4; ++m) {
          const int rowa = wrow + (m << 4) + lr;
          const int ch = ((kk << 2) + kg) ^ (rowa & 7);
          af[m] = *reinterpret_cast<const short8v*>(&lA[0][rowa][ch << 3]);
        }
#pragma unroll
        for (int n = 0; n < 4; ++n) {
          const int rowb = wcol + (n << 4) + lr;
          const int ch = ((kk << 2) + kg) ^ (rowb & 7);
          bf[n] = *reinterpret_cast<const short8v*>(&lB[0][rowb][ch << 3]);
        }
#pragma unroll
        for (int m = 0; m < 4; ++m)
#pragma unroll
          for (int n = 0; n < 4; ++n)
            acc[m][n] = __builtin_amdgcn_mfma_f32_16x16x32_bf16(af[m], bf[n],
                                                                acc[m][n], 0, 0, 0);
      }
    }
    __syncthreads();
  }

  int cseq[4], ctim[4], gcol[4];
#pragma unroll
  for (int n = 0; n < 4; ++n) {
    const int cl = wcol + (n << 4) + lr;
    cseq[n] = mseq_c[cl];
    ctim[n] = mtim_c[cl];
    gcol[n] = col0 + cl;
  }
  float colse[4] = {0.f, 0.f, 0.f, 0.f};
  float colpd[4] = {0.f, 0.f, 0.f, 0.f};
  float colpc[4] = {0.f, 0.f, 0.f, 0.f};

#pragma unroll
  for (int m = 0; m < 4; ++m) {
#pragma unroll
    for (int reg = 0; reg < 4; ++reg) {
      const int rl = wrow + (m << 4) + (kg << 2) + reg;
      const int growg = row0 + rl;
      const int rs = mseq_r[rl];
      const int rt = mtim_r[rl];
      float se = 0.f, pd = 0.f, pcnt = 0.f;
#pragma unroll
      for (int n = 0; n < 4; ++n) {
        const float dot = acc[m][n][reg];
        const float e = exp2f(fmaf(dot, K2C, -K2C));
        const bool nd = (growg != gcol[n]);
        int dt = rt - ctim[n];
        dt = dt < 0 ? -dt : dt;
        const bool pos = nd && (rs == cseq[n]) && (dt < TIME_THR);
        const float ev = nd ? e : 0.f;
        const float dv = pos ? dot : 0.f;
        const float cv = pos ? 1.f : 0.f;
        se += ev;
        pd += dv;
        pcnt += cv;
        if (upper) {
          colse[n] += ev;
          colpd[n] += dv;
          colpc[n] += cv;
        }
      }
#pragma unroll
      for (int s = 1; s < 16; s <<= 1) {
        se += __shfl_xor(se, s);
        pd += __shfl_xor(pd, s);
        pcnt += __shfl_xor(pcnt, s);
      }
      if ((l & 15) == 0) {
        atomicAdd(&p_se[growg], se);
        atomicAdd(&p_ps[growg], pd * INV_T);
        atomicAdd(&p_pc[growg], pcnt);
      }
    }
  }
  if (upper) {
#pragma unroll
    for (int n = 0; n < 4; ++n) {
      float cs = colse[n], cp = colpd[n], cc = colpc[n];
      cs += __shfl_xor(cs, 16);
      cp += __shfl_xor(cp, 16);
      cc += __shfl_xor(cc, 16);
      cs += __shfl_xor(cs, 32);
      cp += __shfl_xor(cp, 32);
      cc += __shfl_xor(cc, 32);
      if (kg == 0) {
        atomicAdd(&p_se[gcol[n]], cs);
        atomicAdd(&p_ps[gcol[n]], cp * INV_T);
        atomicAdd(&p_pc[gcol[n]], cc);
      }
    }
  }
}

__global__ __launch_bounds__(256, 2) void infonce_main1(
    const float* desc, const unsigned short* descb, const int* seq,
    const int* tmid, float* p_se, float* p_ps, float* p_pc, int B, int D,
    int NB) {
  infonce_body<1>(desc, descb, seq, tmid, p_se, p_ps, p_pc, B, D, NB);
}
__global__ __launch_bounds__(256, 2) void infonce_main0(
    const float* desc, const unsigned short* descb, const int* seq,
    const int* tmid, float* p_se, float* p_ps, float* p_pc, int B, int D,
    int NB) {
  infonce_body<0>(desc, descb, seq, tmid, p_se, p_ps, p_pc, B, D, NB);
}

__global__ __launch_bounds__(256) void conv_bf16(const float* __restrict__ in,
                                                 unsigned short* __restrict__ out,
                                                 int n8) {
  const int i = blockIdx.x * 256 + threadIdx.x;
  if (i >= n8) return;
  const float4 f0 = *reinterpret_cast<const float4*>(in + (size_t)i * 8);
  const float4 f1 = *reinterpret_cast<const float4*>(in + (size_t)i * 8 + 4);
  uint4 wv;
  wv.x = pack_bf16x2(f0.x, f0.y);
  wv.y = pack_bf16x2(f0.z, f0.w);
  wv.z = pack_bf16x2(f1.x, f1.y);
  wv.w = pack_bf16x2(f1.z, f1.w);
  *reinterpret_cast<uint4*>(out + (size_t)i * 8) = wv;
}

// one thread per row; slot-major parts -> coalesced loads.
__global__ __launch_bounds__(256) void reduce_parts(
    const float* __restrict__ p_se, const float* __restrict__ p_ps,
    const float* __restrict__ p_pc, float* __restrict__ bnum,
    float* __restrict__ bcnt, int B, int NB) {
  const int tid = threadIdx.x;
  const int row = blockIdx.x * 256 + tid;
  float se = 0.f, ps = 0.f, pc = 0.f;
  for (int j = 0; j < NB; ++j) {
    const size_t o = (size_t)j * B + row;
    se += p_se[o];
    ps += p_ps[o];
    pc += p_pc[o];
  }
  float num = pc * (logf(se) + INV_T) - ps;
  __shared__ float sn[256];
  __shared__ float sc[256];
  sn[tid] = num;
  sc[tid] = pc;
  __syncthreads();
  for (int s = 128; s > 0; s >>= 1) {
    if (tid < s) {
      sn[tid] += sn[tid + s];
      sc[tid] += sc[tid + s];
    }
    __syncthreads();
  }
  if (tid == 0) {
    bnum[blockIdx.x] = sn[0];
    bcnt[blockIdx.x] = sc[0];
  }
}

__global__ __launch_bounds__(256) void final_reduce(
    const float* __restrict__ bnum, const float* __restrict__ bcnt,
    float* __restrict__ out, int n) {
  __shared__ float sn[256];
  __shared__ float sc[256];
  const int tid = threadIdx.x;
  float a = 0.f, b = 0.f;
  for (int i = tid; i < n; i += 256) {
    a += bnum[i];
    b += bcnt[i];
  }
  sn[tid] = a;
  sc[tid] = b;
  __syncthreads();
  for (int s = 128; s > 0; s >>= 1) {
    if (tid < s) {
      sn[tid] += sn[tid + s];
      sc[tid] += sc[tid + s];
    }
    __syncthreads();
  }
  if (tid == 0) out[0] = sn[0] / fmaxf(sc[0], 1.f);
}

__global__ __launch_bounds__(1024) void infonce_finalize(
    const float* __restrict__ a_se, const float* __restrict__ a_ps,
    const float* __restrict__ a_pc, float* __restrict__ out, int B) {
  __shared__ float sn[1024];
  __shared__ float sc[1024];
  const int tid = threadIdx.x;
  float num = 0.f, cnt = 0.f;
  for (int i = tid; i < B; i += 1024) {
    const float c = a_pc[i];
    num += c * (logf(a_se[i]) + INV_T) - a_ps[i];
    cnt += c;
  }
  sn[tid] = num;
  sc[tid] = cnt;
  __syncthreads();
  for (int s = 512; s > 0; s >>= 1) {
    if (tid < s) {
      sn[tid] += sn[tid + s];
      sc[tid] += sc[tid + s];
    }
    __syncthreads();
  }
  if (tid == 0) out[0] = sn[0] / fmaxf(sc[0], 1.f);
}

extern "C" void kernel_launch(void* const* d_in, const int* in_sizes, int n_in,
                              void* d_out, int out_size, void* d_ws, size_t ws_size,
                              hipStream_t stream) {
  (void)n_in;
  (void)out_size;
  const float* desc = (const float*)d_in[0];
  const int* seq = (const int*)d_in[1];
  const int* tmid = (const int*)d_in[2];
  const int B = in_sizes[1];
  const int D = in_sizes[0] / B;
  const int n8 = B * D / 8;
  const size_t descb_bytes = (size_t)B * D * 2;

  if ((B & 255) == 0 && (D & 63) == 0) {
    const int NB = B / 128;
    const int T = NB * (NB + 1) / 2;
    const size_t parts_elems = (size_t)B * NB;
    const size_t nb1 = (size_t)B / 256;
    const size_t need = descb_bytes + 3 * parts_elems * 4 + 2 * nb1 * 4;
    if (ws_size >= need) {
      unsigned short* descb = (unsigned short*)d_ws;
      float* p_se = (float*)((char*)d_ws + descb_bytes);
      float* p_ps = p_se + parts_elems;
      float* p_pc = p_ps + parts_elems;
      float* bnum = p_pc + parts_elems;
      float* bcnt = bnum + nb1;
      conv_bf16<<<(n8 + 255) / 256, 256, 0, stream>>>(desc, descb, n8);
      gram128s<<<T, 256, 0, stream>>>(descb, seq, tmid, p_se, p_ps, p_pc, B, D, NB);
      reduce_parts<<<(int)nb1, 256, 0, stream>>>(p_se, p_ps, p_pc, bnum, bcnt, B, NB);
      final_reduce<<<1, 256, 0, stream>>>(bnum, bcnt, (float*)d_out, (int)nb1);
      return;
    }
  }
  // fallbacks: 128^2 kernel with atomic epilogue
  const int NB = B / 128;
  const int T = NB * (NB + 1) / 2;
  const size_t need1 = (size_t)3 * B * 4 + descb_bytes;
  float* a_se = (float*)d_ws;
  float* a_ps = a_se + B;
  float* a_pc = a_ps + B;
  hipMemsetAsync(d_ws, 0, (size_t)3 * B * sizeof(float), stream);
  if (ws_size >= need1) {
    unsigned short* descb = (unsigned short*)((char*)d_ws + (size_t)3 * B * 4);
    conv_bf16<<<(n8 + 255) / 256, 256, 0, stream>>>(desc, descb, n8);
    infonce_main1<<<T, 256, 0, stream>>>(desc, descb, seq, tmid, a_se, a_ps,
                                         a_pc, B, D, NB);
  } else {
    infonce_main0<<<T, 256, 0, stream>>>(desc, nullptr, seq, tmid, a_se, a_ps,
                                         a_pc, B, D, NB);
  }
  infonce_finalize<<<1, 1024, 0, stream>>>(a_se, a_ps, a_pc, (float*)d_out, B);
}

// Round 12
// 106.227 us; speedup vs baseline: 2.7840x; 2.7840x over previous
//
#include <hip/hip_runtime.h>
#include <math.h>

#define TILE 128

typedef __attribute__((ext_vector_type(8))) short short8v;
typedef __attribute__((ext_vector_type(4))) float f32x4;

// constants: 1/T and 1/(T*ln2)
#define INV_T 14.285714285714286f
#define K2C   20.60992915f
#define TIME_THR 5000000

__device__ __forceinline__ unsigned pack_bf16x2(float lo, float hi) {
  unsigned a = __float_as_uint(lo);
  unsigned b = __float_as_uint(hi);
  a = (a + 0x7FFFu + ((a >> 16) & 1u)) >> 16;
  b = (b + 0x7FFFu + ((b >> 16) & 1u)) & 0xFFFF0000u;
  return b | a;
}

__device__ __forceinline__ void gl_lds16(const void* g, void* l) {
  __builtin_amdgcn_global_load_lds(
      (const __attribute__((address_space(1))) unsigned int*)g,
      (__attribute__((address_space(3))) unsigned int*)l, 16, 0, 0);
}

// MODE=2: bf16 src + gl_lds staging + counted-vmcnt pipeline (T4) +
//         atomic-free partials epilogue. R7-proven geometry (112 VGPR,
//         2 blocks/CU — the only register-budget point that fits; see
//         R8-R11: any >2 waves/EU config splits the unified file too
//         small and spills 175-660MB to scratch).
//         R12 change vs R7: stage BOTH next panels at step top, vmcnt(8)
//         -> full-step latency cover for B-panel too (was MFMA-only).
// MODE=1: same pipeline + atomicAdd epilogue (fallback).
// MODE=0: fp32 src, register staging + conversion + atomicAdd (fallback).
template <int MODE>
__device__ __forceinline__ void infonce_body(
    const float* __restrict__ desc, const unsigned short* __restrict__ descb,
    const int* __restrict__ seq, const int* __restrict__ tmid,
    float* __restrict__ p_se, float* __restrict__ p_ps,
    float* __restrict__ p_pc, int B, int D, int NB) {
  __shared__ __align__(16) unsigned short lA[2][TILE][64];
  __shared__ __align__(16) unsigned short lB[2][TILE][64];
  __shared__ int mseq_r[TILE], mtim_r[TILE], mseq_c[TILE], mtim_c[TILE];

  // ---- triangular (upper) block decode, with XCD-aware swizzle ----
  const int T = NB * (NB + 1) / 2;
  int t = blockIdx.x;
  if ((T & 7) == 0) t = (t & 7) * (T >> 3) + (t >> 3);
  float fn = (float)NB + 0.5f;
  int r = (int)(fn - sqrtf(fmaxf(fn * fn - 2.0f * (float)t, 0.0f)));
  if (r < 0) r = 0;
  if (r > NB - 1) r = NB - 1;
  auto Sf = [NB](int rr) { return rr * NB - ((rr * (rr - 1)) >> 1); };
  while (r > 0 && Sf(r) > t) --r;
  while (r < NB - 1 && Sf(r + 1) <= t) ++r;
  const int rb = r;
  const int cb = rb + (t - Sf(rb));
  const bool upper = (cb != rb);

  const int row0 = rb * TILE;
  const int col0 = cb * TILE;

  const int tid = threadIdx.x;
  const int l = tid & 63;
  const int w = tid >> 6;          // wave id 0..3 (2x2)
  const int wrow = (w >> 1) << 6;  // 0 or 64
  const int wcol = (w & 1) << 6;   // 0 or 64
  const int lr = l & 15;
  const int kg = l >> 4;

  // stage row/col metadata (before prologue stages so vmcnt counting is exact)
  if (tid < TILE) {
    mseq_r[tid] = seq[row0 + tid];
    mtim_r[tid] = tmid[row0 + tid];
    mseq_c[tid] = seq[col0 + tid];
    mtim_c[tid] = tmid[col0 + tid];
  }

  f32x4 acc[4][4];
#pragma unroll
  for (int m = 0; m < 4; ++m)
#pragma unroll
    for (int n = 0; n < 4; ++n) acc[m][n] = (f32x4){0.f, 0.f, 0.f, 0.f};

  // staging geometry (MODE>=1): granule g = q*256 + tid covers
  // row rg = q*32 + (tid>>3), slot s = tid&7. Linear LDS dest (rule #21);
  // source chunk pre-swizzled: c8 = (l&7) ^ ((l>>3)&7) == s ^ (rg&7).
  const int c8 = (l & 7) ^ ((l >> 3) & 7);
  const int rbase = (w << 3) + (l >> 3);

  // MODE=0 staging geometry
  const int sr = tid >> 3;
  const int sc = tid & 7;

  const int NT = D >> 6;

  if (MODE >= 1) {
    // 4 gl_lds per thread per call; each is one vmcnt event.
    auto stageA = [&](int tt) {
      const int bu = tt & 1;
      const int k0 = tt << 6;
#pragma unroll
      for (int q = 0; q < 4; ++q) {
        const int rg = (q << 5) + rbase;
        gl_lds16(descb + (size_t)(row0 + rg) * D + k0 + (c8 << 3),
                 (char*)&lA[bu][0][0] + (q << 12) + (w << 10));
      }
    };
    auto stageB = [&](int tt) {
      const int bu = tt & 1;
      const int k0 = tt << 6;
#pragma unroll
      for (int q = 0; q < 4; ++q) {
        const int rg = (q << 5) + rbase;
        gl_lds16(descb + (size_t)(col0 + rg) * D + k0 + (c8 << 3),
                 (char*)&lB[bu][0][0] + (q << 12) + (w << 10));
      }
    };

    __builtin_amdgcn_sched_barrier(0);
    stageA(0);
    stageB(0);
    __builtin_amdgcn_sched_barrier(0);

    for (int ts = 0; ts < NT; ++ts) {
      const int bu = ts & 1;
      // issue BOTH next panels early; counted wait drains only tile ts's 8
      if (ts + 1 < NT) {
        stageA(ts + 1);
        stageB(ts + 1);
        __builtin_amdgcn_sched_barrier(0);
        asm volatile("s_waitcnt vmcnt(8)" ::: "memory");
      } else {
        asm volatile("s_waitcnt vmcnt(0)" ::: "memory");
      }
      __builtin_amdgcn_sched_barrier(0);
      __builtin_amdgcn_s_barrier();  // buf[bu] globally ready
      __builtin_amdgcn_sched_barrier(0);

      short8v af[2][4], bf[2][4];
#pragma unroll
      for (int kk = 0; kk < 2; ++kk) {
#pragma unroll
        for (int m = 0; m < 4; ++m) {
          const int rowa = wrow + (m << 4) + lr;
          const int ch = ((kk << 2) + kg) ^ (rowa & 7);
          af[kk][m] = *reinterpret_cast<const short8v*>(&lA[bu][rowa][ch << 3]);
        }
#pragma unroll
        for (int n = 0; n < 4; ++n) {
          const int rowb = wcol + (n << 4) + lr;
          const int ch = ((kk << 2) + kg) ^ (rowb & 7);
          bf[kk][n] = *reinterpret_cast<const short8v*>(&lB[bu][rowb][ch << 3]);
        }
      }
      __builtin_amdgcn_sched_barrier(0);
      asm volatile("s_waitcnt lgkmcnt(0)" ::: "memory");
      __builtin_amdgcn_sched_barrier(0);  // rule #18: pin MFMA below the wait
      __builtin_amdgcn_s_setprio(1);
#pragma unroll
      for (int kk = 0; kk < 2; ++kk)
#pragma unroll
        for (int m = 0; m < 4; ++m)
#pragma unroll
          for (int n = 0; n < 4; ++n)
            acc[m][n] = __builtin_amdgcn_mfma_f32_16x16x32_bf16(
                af[kk][m], bf[kk][n], acc[m][n], 0, 0, 0);
      __builtin_amdgcn_s_setprio(0);
      __builtin_amdgcn_sched_barrier(0);
      __builtin_amdgcn_s_barrier();  // all waves done reading buf[bu]
    }
    __syncthreads();  // full drain before LDS reuse in epilogue
  } else {
    // MODE 0 fallback: fp32 + in-loop conversion, simple 2-barrier loop
    for (int k0 = 0; k0 < D; k0 += 64) {
      __syncthreads();
#pragma unroll
      for (int p = 0; p < 4; ++p) {
        const int rr = (p << 5) + sr;
        const float* gA = desc + (size_t)(row0 + rr) * D + k0 + (sc << 3);
        const float4 fa0 = *reinterpret_cast<const float4*>(gA);
        const float4 fa1 = *reinterpret_cast<const float4*>(gA + 4);
        const float* gB = desc + (size_t)(col0 + rr) * D + k0 + (sc << 3);
        const float4 fb0 = *reinterpret_cast<const float4*>(gB);
        const float4 fb1 = *reinterpret_cast<const float4*>(gB + 4);
        uint4 wa, wb;
        wa.x = pack_bf16x2(fa0.x, fa0.y);
        wa.y = pack_bf16x2(fa0.z, fa0.w);
        wa.z = pack_bf16x2(fa1.x, fa1.y);
        wa.w = pack_bf16x2(fa1.z, fa1.w);
        wb.x = pack_bf16x2(fb0.x, fb0.y);
        wb.y = pack_bf16x2(fb0.z, fb0.w);
        wb.z = pack_bf16x2(fb1.x, fb1.y);
        wb.w = pack_bf16x2(fb1.z, fb1.w);
        const int dst = (sc ^ (rr & 7)) << 3;
        *reinterpret_cast<uint4*>(&lA[0][rr][dst]) = wa;
        *reinterpret_cast<uint4*>(&lB[0][rr][dst]) = wb;
      }
      __syncthreads();
#pragma unroll
      for (int kk = 0; kk < 2; ++kk) {
        short8v af[4], bf[4];
#pragma unroll
        for (int m = 0; m < 4; ++m) {
          const int rowa = wrow + (m << 4) + lr;
          const int ch = ((kk << 2) + kg) ^ (rowa & 7);
          af[m] = *reinterpret_cast<const short8v*>(&lA[0][rowa][ch << 3]);
        }
#pragma unroll
        for (int n = 0; n < 4; ++n) {
          const int rowb = wcol + (n << 4) + lr;
          const int ch = ((kk << 2) + kg) ^ (rowb & 7);
          bf[n] = *reinterpret_cast<const short8v*>(&lB[0][rowb][ch << 3]);
        }
#pragma unroll
        for (int m = 0; m < 4; ++m)
#pragma unroll
          for (int n = 0; n < 4; ++n)
            acc[m][n] = __builtin_amdgcn_mfma_f32_16x16x32_bf16(af[m], bf[n],
                                                                acc[m][n], 0, 0, 0);
      }
    }
    __syncthreads();
  }

  // LDS reuse for MODE=2 cross-wave combine (lA/lB are dead after K-loop).
  float* rowred = (float*)&lA[0][0][0];  // [2][TILE][3]
  float* colred = (float*)&lB[0][0][0];  // [2][TILE][3]

  // ---- epilogue: per-row (and per-col if upper) partial sums ----
  int cseq[4], ctim[4], gcol[4];
#pragma unroll
  for (int n = 0; n < 4; ++n) {
    const int cl = wcol + (n << 4) + lr;
    cseq[n] = mseq_c[cl];
    ctim[n] = mtim_c[cl];
    gcol[n] = col0 + cl;
  }
  float colse[4] = {0.f, 0.f, 0.f, 0.f};
  float colpd[4] = {0.f, 0.f, 0.f, 0.f};
  float colpc[4] = {0.f, 0.f, 0.f, 0.f};

#pragma unroll
  for (int m = 0; m < 4; ++m) {
#pragma unroll
    for (int reg = 0; reg < 4; ++reg) {
      const int rl = wrow + (m << 4) + (kg << 2) + reg;  // row within tile
      const int growg = row0 + rl;
      const int rs = mseq_r[rl];
      const int rt = mtim_r[rl];
      float se = 0.f, pd = 0.f, pcnt = 0.f;
#pragma unroll
      for (int n = 0; n < 4; ++n) {
        const float dot = acc[m][n][reg];
        const float e = exp2f(fmaf(dot, K2C, -K2C));
        const bool nd = (growg != gcol[n]);
        int dt = rt - ctim[n];
        dt = dt < 0 ? -dt : dt;
        const bool pos = nd && (rs == cseq[n]) && (dt < TIME_THR);
        const float ev = nd ? e : 0.f;
        const float dv = pos ? dot : 0.f;
        const float cv = pos ? 1.f : 0.f;
        se += ev;
        pd += dv;
        pcnt += cv;
        if (upper) {
          colse[n] += ev;
          colpd[n] += dv;
          colpc[n] += cv;
        }
      }
      // reduce across the 16 lanes that share this row
#pragma unroll
      for (int s = 1; s < 16; s <<= 1) {
        se += __shfl_xor(se, s);
        pd += __shfl_xor(pd, s);
        pcnt += __shfl_xor(pcnt, s);
      }
      if ((l & 15) == 0) {
        if (MODE == 2) {
          const int half = wcol >> 6;
          float* rr3 = rowred + ((size_t)(half * TILE + rl)) * 3;
          rr3[0] = se;
          rr3[1] = pd;
          rr3[2] = pcnt;
        } else {
          atomicAdd(&p_se[growg], se);
          atomicAdd(&p_ps[growg], pd * INV_T);
          atomicAdd(&p_pc[growg], pcnt);
        }
      }
    }
  }
  if (upper) {
    // column sums = row sums of the mirrored (transposed) tile
#pragma unroll
    for (int n = 0; n < 4; ++n) {
      float cs = colse[n], cp = colpd[n], cc = colpc[n];
      cs += __shfl_xor(cs, 16);
      cp += __shfl_xor(cp, 16);
      cc += __shfl_xor(cc, 16);
      cs += __shfl_xor(cs, 32);
      cp += __shfl_xor(cp, 32);
      cc += __shfl_xor(cc, 32);
      if (kg == 0) {
        if (MODE == 2) {
          const int half = wrow >> 6;
          const int cl = wcol + (n << 4) + lr;
          float* cr3 = colred + ((size_t)(half * TILE + cl)) * 3;
          cr3[0] = cs;
          cr3[1] = cp;
          cr3[2] = cc;
        } else {
          atomicAdd(&p_se[gcol[n]], cs);
          atomicAdd(&p_ps[gcol[n]], cp * INV_T);
          atomicAdd(&p_pc[gcol[n]], cc);
        }
      }
    }
  }

  if (MODE == 2) {
    __syncthreads();  // rowred/colred complete
    if (tid < TILE) {
      const int row = tid;
      const float se = rowred[(size_t)row * 3 + 0] + rowred[(size_t)(TILE + row) * 3 + 0];
      const float pd = rowred[(size_t)row * 3 + 1] + rowred[(size_t)(TILE + row) * 3 + 1];
      const float pc = rowred[(size_t)row * 3 + 2] + rowred[(size_t)(TILE + row) * 3 + 2];
      const size_t o = (size_t)cb * B + row0 + row;  // slot-major, coalesced
      p_se[o] = se;
      p_ps[o] = pd * INV_T;
      p_pc[o] = pc;
    } else if (upper && tid < 2 * TILE) {
      const int col = tid - TILE;
      const float se = colred[(size_t)col * 3 + 0] + colred[(size_t)(TILE + col) * 3 + 0];
      const float pd = colred[(size_t)col * 3 + 1] + colred[(size_t)(TILE + col) * 3 + 1];
      const float pc = colred[(size_t)col * 3 + 2] + colred[(size_t)(TILE + col) * 3 + 2];
      const size_t o = (size_t)rb * B + col0 + col;  // slot-major, coalesced
      p_se[o] = se;
      p_ps[o] = pd * INV_T;
      p_pc[o] = pc;
    }
  }
}

__global__ __launch_bounds__(256, 2) void infonce_main2(
    const float* desc, const unsigned short* descb, const int* seq,
    const int* tmid, float* p_se, float* p_ps, float* p_pc, int B, int D,
    int NB) {
  infonce_body<2>(desc, descb, seq, tmid, p_se, p_ps, p_pc, B, D, NB);
}
__global__ __launch_bounds__(256, 2) void infonce_main1(
    const float* desc, const unsigned short* descb, const int* seq,
    const int* tmid, float* p_se, float* p_ps, float* p_pc, int B, int D,
    int NB) {
  infonce_body<1>(desc, descb, seq, tmid, p_se, p_ps, p_pc, B, D, NB);
}
__global__ __launch_bounds__(256, 2) void infonce_main0(
    const float* desc, const unsigned short* descb, const int* seq,
    const int* tmid, float* p_se, float* p_ps, float* p_pc, int B, int D,
    int NB) {
  infonce_body<0>(desc, descb, seq, tmid, p_se, p_ps, p_pc, B, D, NB);
}

__global__ __launch_bounds__(256) void conv_bf16(const float* __restrict__ in,
                                                 unsigned short* __restrict__ out,
                                                 int n8) {
  const int i = blockIdx.x * 256 + threadIdx.x;
  if (i >= n8) return;
  const float4 f0 = *reinterpret_cast<const float4*>(in + (size_t)i * 8);
  const float4 f1 = *reinterpret_cast<const float4*>(in + (size_t)i * 8 + 4);
  uint4 wv;
  wv.x = pack_bf16x2(f0.x, f0.y);
  wv.y = pack_bf16x2(f0.z, f0.w);
  wv.z = pack_bf16x2(f1.x, f1.y);
  wv.w = pack_bf16x2(f1.z, f1.w);
  *reinterpret_cast<uint4*>(out + (size_t)i * 8) = wv;
}

// 4 threads per row (NB quarters), 64 rows/block -> B/64 blocks.
// (old 1-thread-per-row used only 32 blocks = 1/8 of CUs)
__global__ __launch_bounds__(256) void reduce_parts4(
    const float* __restrict__ p_se, const float* __restrict__ p_ps,
    const float* __restrict__ p_pc, float* __restrict__ bnum,
    float* __restrict__ bcnt, int B, int NB) {
  const int tid = threadIdx.x;
  const int rloc = tid & 63;
  const int chunk = tid >> 6;  // 0..3
  const int row = blockIdx.x * 64 + rloc;
  const int jpc = NB >> 2;
  float se = 0.f, ps = 0.f, pc = 0.f;
  for (int j = chunk * jpc; j < (chunk + 1) * jpc; ++j) {
    const size_t o = (size_t)j * B + row;
    se += p_se[o];
    ps += p_ps[o];
    pc += p_pc[o];
  }
  __shared__ float s3[3][4][64];
  s3[0][chunk][rloc] = se;
  s3[1][chunk][rloc] = ps;
  s3[2][chunk][rloc] = pc;
  __syncthreads();
  if (tid < 64) {
    const float tse = s3[0][0][tid] + s3[0][1][tid] + s3[0][2][tid] + s3[0][3][tid];
    const float tps = s3[1][0][tid] + s3[1][1][tid] + s3[1][2][tid] + s3[1][3][tid];
    const float tpc = s3[2][0][tid] + s3[2][1][tid] + s3[2][2][tid] + s3[2][3][tid];
    float a = tpc * (logf(tse) + INV_T) - tps;
    float b = tpc;
#pragma unroll
    for (int s = 1; s < 64; s <<= 1) {
      a += __shfl_xor(a, s);
      b += __shfl_xor(b, s);
    }
    if (tid == 0) {
      bnum[blockIdx.x] = a;
      bcnt[blockIdx.x] = b;
    }
  }
}

// fallback: one thread per row; slot-major parts -> coalesced loads.
__global__ __launch_bounds__(256) void reduce_parts(
    const float* __restrict__ p_se, const float* __restrict__ p_ps,
    const float* __restrict__ p_pc, float* __restrict__ bnum,
    float* __restrict__ bcnt, int B, int NB) {
  const int tid = threadIdx.x;
  const int row = blockIdx.x * 256 + tid;
  float se = 0.f, ps = 0.f, pc = 0.f;
  for (int j = 0; j < NB; ++j) {
    const size_t o = (size_t)j * B + row;
    se += p_se[o];
    ps += p_ps[o];
    pc += p_pc[o];
  }
  float num = pc * (logf(se) + INV_T) - ps;
  __shared__ float sn[256];
  __shared__ float sc[256];
  sn[tid] = num;
  sc[tid] = pc;
  __syncthreads();
  for (int s = 128; s > 0; s >>= 1) {
    if (tid < s) {
      sn[tid] += sn[tid + s];
      sc[tid] += sc[tid + s];
    }
    __syncthreads();
  }
  if (tid == 0) {
    bnum[blockIdx.x] = sn[0];
    bcnt[blockIdx.x] = sc[0];
  }
}

__global__ __launch_bounds__(256) void final_reduce(
    const float* __restrict__ bnum, const float* __restrict__ bcnt,
    float* __restrict__ out, int n) {
  __shared__ float sn[256];
  __shared__ float sc[256];
  const int tid = threadIdx.x;
  float a = 0.f, b = 0.f;
  for (int i = tid; i < n; i += 256) {
    a += bnum[i];
    b += bcnt[i];
  }
  sn[tid] = a;
  sc[tid] = b;
  __syncthreads();
  for (int s = 128; s > 0; s >>= 1) {
    if (tid < s) {
      sn[tid] += sn[tid + s];
      sc[tid] += sc[tid + s];
    }
    __syncthreads();
  }
  if (tid == 0) out[0] = sn[0] / fmaxf(sc[0], 1.f);
}

// fallback finalize for atomic modes (reads flat a_se/a_ps/a_pc)
__global__ __launch_bounds__(1024) void infonce_finalize(
    const float* __restrict__ a_se, const float* __restrict__ a_ps,
    const float* __restrict__ a_pc, float* __restrict__ out, int B) {
  __shared__ float sn[1024];
  __shared__ float sc[1024];
  const int tid = threadIdx.x;
  float num = 0.f, cnt = 0.f;
  for (int i = tid; i < B; i += 1024) {
    const float c = a_pc[i];
    num += c * (logf(a_se[i]) + INV_T) - a_ps[i];
    cnt += c;
  }
  sn[tid] = num;
  sc[tid] = cnt;
  __syncthreads();
  for (int s = 512; s > 0; s >>= 1) {
    if (tid < s) {
      sn[tid] += sn[tid + s];
      sc[tid] += sc[tid + s];
    }
    __syncthreads();
  }
  if (tid == 0) out[0] = sn[0] / fmaxf(sc[0], 1.f);
}

extern "C" void kernel_launch(void* const* d_in, const int* in_sizes, int n_in,
                              void* d_out, int out_size, void* d_ws, size_t ws_size,
                              hipStream_t stream) {
  (void)n_in;
  (void)out_size;
  const float* desc = (const float*)d_in[0];
  const int* seq = (const int*)d_in[1];
  const int* tmid = (const int*)d_in[2];
  const int B = in_sizes[1];
  const int D = in_sizes[0] / B;
  const int NB = B / TILE;
  const int T = NB * (NB + 1) / 2;
  const int n8 = B * D / 8;

  const size_t descb_bytes = (size_t)B * D * 2;
  const size_t parts_elems = (size_t)B * NB;
  const size_t nb1 = (size_t)B / 64;  // reduce_parts4 blocks (max case)
  const size_t need2 = descb_bytes + 3 * parts_elems * 4 + 2 * nb1 * 4;
  const size_t need1 = (size_t)3 * B * 4 + descb_bytes;

  if ((B & 255) == 0 && (D & 63) == 0 && ws_size >= need2) {
    // MODE 2: atomic-free
    unsigned short* descb = (unsigned short*)d_ws;
    float* p_se = (float*)((char*)d_ws + descb_bytes);
    float* p_ps = p_se + parts_elems;
    float* p_pc = p_ps + parts_elems;
    float* bnum = p_pc + parts_elems;
    float* bcnt = bnum + nb1;
    conv_bf16<<<(n8 + 255) / 256, 256, 0, stream>>>(desc, descb, n8);
    infonce_main2<<<T, 256, 0, stream>>>(desc, descb, seq, tmid, p_se, p_ps,
                                         p_pc, B, D, NB);
    if ((NB & 3) == 0 && (B & 63) == 0) {
      const int nrb = B / 64;
      reduce_parts4<<<nrb, 256, 0, stream>>>(p_se, p_ps, p_pc, bnum, bcnt, B, NB);
      final_reduce<<<1, 256, 0, stream>>>(bnum, bcnt, (float*)d_out, nrb);
    } else {
      const int nrb = B / 256;
      reduce_parts<<<nrb, 256, 0, stream>>>(p_se, p_ps, p_pc, bnum, bcnt, B, NB);
      final_reduce<<<1, 256, 0, stream>>>(bnum, bcnt, (float*)d_out, nrb);
    }
  } else if (ws_size >= need1) {
    float* a_se = (float*)d_ws;
    float* a_ps = a_se + B;
    float* a_pc = a_ps + B;
    unsigned short* descb = (unsigned short*)((char*)d_ws + (size_t)3 * B * 4);
    hipMemsetAsync(d_ws, 0, (size_t)3 * B * sizeof(float), stream);
    conv_bf16<<<(n8 + 255) / 256, 256, 0, stream>>>(desc, descb, n8);
    infonce_main1<<<T, 256, 0, stream>>>(desc, descb, seq, tmid, a_se, a_ps,
                                         a_pc, B, D, NB);
    infonce_finalize<<<1, 1024, 0, stream>>>(a_se, a_ps, a_pc, (float*)d_out, B);
  } else {
    float* a_se = (float*)d_ws;
    float* a_ps = a_se + B;
    float* a_pc = a_ps + B;
    hipMemsetAsync(d_ws, 0, (size_t)3 * B * sizeof(float), stream);
    infonce_main0<<<T, 256, 0, stream>>>(desc, nullptr, seq, tmid, a_se, a_ps,
                                         a_pc, B, D, NB);
    infonce_finalize<<<1, 1024, 0, stream>>>(a_se, a_ps, a_pc, (float*)d_out, B);
  }
}

// Round 13
// 103.704 us; speedup vs baseline: 2.8517x; 1.0243x over previous
//
#include <hip/hip_runtime.h>
#include <math.h>

#define TILE 128

typedef __attribute__((ext_vector_type(8))) short short8v;
typedef __attribute__((ext_vector_type(4))) float f32x4;

// constants: 1/T and 1/(T*ln2)
#define INV_T 14.285714285714286f
#define K2C   20.60992915f
#define TIME_THR 5000000

__device__ __forceinline__ unsigned pack_bf16x2(float lo, float hi) {
  unsigned a = __float_as_uint(lo);
  unsigned b = __float_as_uint(hi);
  a = (a + 0x7FFFu + ((a >> 16) & 1u)) >> 16;
  b = (b + 0x7FFFu + ((b >> 16) & 1u)) & 0xFFFF0000u;
  return b | a;
}

__device__ __forceinline__ void gl_lds16(const void* g, void* l) {
  __builtin_amdgcn_global_load_lds(
      (const __attribute__((address_space(1))) unsigned int*)g,
      (__attribute__((address_space(3))) unsigned int*)l, 16, 0, 0);
}

// MODE=2: bf16 src + gl_lds staging + counted-vmcnt pipeline + atomic-free
//         partials epilogue. R7 geometry (112 VGPR, 2 blocks/CU — the only
//         register-budget point that fits; R8-R11: >2 waves/EU splits the
//         unified file too small -> 175-660MB scratch).
//         R13: (a) kk-split ds_reads with lgkmcnt(8) -> kk0 MFMAs overlap
//         kk1 reads (DS completes in-order per wave); (b) staging pointers
//         hoisted + advanced by 64/step (sched_barrier walls were forcing
//         full addr recomputation every step).
// MODE=1: same pipeline + atomicAdd epilogue (fallback).
// MODE=0: fp32 src, register staging + conversion + atomicAdd (fallback).
template <int MODE>
__device__ __forceinline__ void infonce_body(
    const float* __restrict__ desc, const unsigned short* __restrict__ descb,
    const int* __restrict__ seq, const int* __restrict__ tmid,
    float* __restrict__ p_se, float* __restrict__ p_ps,
    float* __restrict__ p_pc, int B, int D, int NB) {
  __shared__ __align__(16) unsigned short lA[2][TILE][64];
  __shared__ __align__(16) unsigned short lB[2][TILE][64];
  __shared__ int mseq_r[TILE], mtim_r[TILE], mseq_c[TILE], mtim_c[TILE];

  // ---- triangular (upper) block decode, with XCD-aware swizzle ----
  const int T = NB * (NB + 1) / 2;
  int t = blockIdx.x;
  if ((T & 7) == 0) t = (t & 7) * (T >> 3) + (t >> 3);
  float fn = (float)NB + 0.5f;
  int r = (int)(fn - sqrtf(fmaxf(fn * fn - 2.0f * (float)t, 0.0f)));
  if (r < 0) r = 0;
  if (r > NB - 1) r = NB - 1;
  auto Sf = [NB](int rr) { return rr * NB - ((rr * (rr - 1)) >> 1); };
  while (r > 0 && Sf(r) > t) --r;
  while (r < NB - 1 && Sf(r + 1) <= t) ++r;
  const int rb = r;
  const int cb = rb + (t - Sf(rb));
  const bool upper = (cb != rb);

  const int row0 = rb * TILE;
  const int col0 = cb * TILE;

  const int tid = threadIdx.x;
  const int l = tid & 63;
  const int w = tid >> 6;          // wave id 0..3 (2x2)
  const int wrow = (w >> 1) << 6;  // 0 or 64
  const int wcol = (w & 1) << 6;   // 0 or 64
  const int lr = l & 15;
  const int kg = l >> 4;

  // stage row/col metadata (before prologue stages so vmcnt counting is exact)
  if (tid < TILE) {
    mseq_r[tid] = seq[row0 + tid];
    mtim_r[tid] = tmid[row0 + tid];
    mseq_c[tid] = seq[col0 + tid];
    mtim_c[tid] = tmid[col0 + tid];
  }

  f32x4 acc[4][4];
#pragma unroll
  for (int m = 0; m < 4; ++m)
#pragma unroll
    for (int n = 0; n < 4; ++n) acc[m][n] = (f32x4){0.f, 0.f, 0.f, 0.f};

  // staging geometry (MODE>=1): granule g = q*256 + tid covers
  // row rg = q*32 + (tid>>3), slot s = tid&7. Linear LDS dest (rule #21);
  // source chunk pre-swizzled: c8 = (l&7) ^ ((l>>3)&7) == s ^ (rg&7).
  const int c8 = (l & 7) ^ ((l >> 3) & 7);
  const int rbase = (w << 3) + (l >> 3);

  // MODE=0 staging geometry
  const int sr = tid >> 3;
  const int sc = tid & 7;

  const int NT = D >> 6;

  if (MODE >= 1) {
    // hoisted staging pointers; advanced +64 elements per K-step.
    const unsigned short* pA[4];
    const unsigned short* pB[4];
#pragma unroll
    for (int q = 0; q < 4; ++q) {
      const int rg = (q << 5) + rbase;
      pA[q] = descb + (size_t)(row0 + rg) * D + (c8 << 3);
      pB[q] = descb + (size_t)(col0 + rg) * D + (c8 << 3);
    }
    auto stageA = [&](int bu_) {
#pragma unroll
      for (int q = 0; q < 4; ++q)
        gl_lds16(pA[q], (char*)&lA[bu_][0][0] + (q << 12) + (w << 10));
    };
    auto stageB = [&](int bu_) {
#pragma unroll
      for (int q = 0; q < 4; ++q)
        gl_lds16(pB[q], (char*)&lB[bu_][0][0] + (q << 12) + (w << 10));
    };

    __builtin_amdgcn_sched_barrier(0);
    stageA(0);
    stageB(0);
    __builtin_amdgcn_sched_barrier(0);
#pragma unroll
    for (int q = 0; q < 4; ++q) {
      pA[q] += 64;
      pB[q] += 64;
    }

    for (int ts = 0; ts < NT; ++ts) {
      const int bu = ts & 1;
      // issue next A-panel; counted wait drains only tile ts's 8 events
      if (ts + 1 < NT) {
        stageA(bu ^ 1);
        __builtin_amdgcn_sched_barrier(0);
        asm volatile("s_waitcnt vmcnt(4)" ::: "memory");
      } else {
        asm volatile("s_waitcnt vmcnt(0)" ::: "memory");
      }
      __builtin_amdgcn_sched_barrier(0);
      __builtin_amdgcn_s_barrier();  // buf[bu] globally ready
      __builtin_amdgcn_sched_barrier(0);

      short8v af[2][4], bf[2][4];
      // ---- batch kk=0 (8 reads) ----
#pragma unroll
      for (int m = 0; m < 4; ++m) {
        const int rowa = wrow + (m << 4) + lr;
        const int ch = kg ^ (rowa & 7);
        af[0][m] = *reinterpret_cast<const short8v*>(&lA[bu][rowa][ch << 3]);
      }
#pragma unroll
      for (int n = 0; n < 4; ++n) {
        const int rowb = wcol + (n << 4) + lr;
        const int ch = kg ^ (rowb & 7);
        bf[0][n] = *reinterpret_cast<const short8v*>(&lB[bu][rowb][ch << 3]);
      }
      __builtin_amdgcn_sched_barrier(0);
      // ---- batch kk=1 (8 reads) ----
#pragma unroll
      for (int m = 0; m < 4; ++m) {
        const int rowa = wrow + (m << 4) + lr;
        const int ch = (4 + kg) ^ (rowa & 7);
        af[1][m] = *reinterpret_cast<const short8v*>(&lA[bu][rowa][ch << 3]);
      }
#pragma unroll
      for (int n = 0; n < 4; ++n) {
        const int rowb = wcol + (n << 4) + lr;
        const int ch = (4 + kg) ^ (rowb & 7);
        bf[1][n] = *reinterpret_cast<const short8v*>(&lB[bu][rowb][ch << 3]);
      }
      __builtin_amdgcn_sched_barrier(0);
      if (ts + 1 < NT) stageB(bu ^ 1);  // mid-step; lands by ts+1's vmcnt(4)
      __builtin_amdgcn_sched_barrier(0);
#pragma unroll
      for (int q = 0; q < 4; ++q) {
        pA[q] += 64;
        pB[q] += 64;
      }
      __builtin_amdgcn_sched_barrier(0);
      // wait only the first 8 ds_reads (DS completes in-order per wave);
      // kk=0 MFMAs run while kk=1 reads drain.
      asm volatile("s_waitcnt lgkmcnt(8)" ::: "memory");
      __builtin_amdgcn_sched_barrier(0);  // rule #18
      __builtin_amdgcn_s_setprio(1);
#pragma unroll
      for (int m = 0; m < 4; ++m)
#pragma unroll
        for (int n = 0; n < 4; ++n)
          acc[m][n] = __builtin_amdgcn_mfma_f32_16x16x32_bf16(
              af[0][m], bf[0][n], acc[m][n], 0, 0, 0);
      __builtin_amdgcn_sched_barrier(0);
      asm volatile("s_waitcnt lgkmcnt(0)" ::: "memory");
      __builtin_amdgcn_sched_barrier(0);  // rule #18
#pragma unroll
      for (int m = 0; m < 4; ++m)
#pragma unroll
        for (int n = 0; n < 4; ++n)
          acc[m][n] = __builtin_amdgcn_mfma_f32_16x16x32_bf16(
              af[1][m], bf[1][n], acc[m][n], 0, 0, 0);
      __builtin_amdgcn_s_setprio(0);
      __builtin_amdgcn_sched_barrier(0);
      __builtin_amdgcn_s_barrier();  // all waves done reading buf[bu]
    }
    __syncthreads();  // full drain before LDS reuse in epilogue
  } else {
    // MODE 0 fallback: fp32 + in-loop conversion, simple 2-barrier loop
    for (int k0 = 0; k0 < D; k0 += 64) {
      __syncthreads();
#pragma unroll
      for (int p = 0; p < 4; ++p) {
        const int rr = (p << 5) + sr;
        const float* gA = desc + (size_t)(row0 + rr) * D + k0 + (sc << 3);
        const float4 fa0 = *reinterpret_cast<const float4*>(gA);
        const float4 fa1 = *reinterpret_cast<const float4*>(gA + 4);
        const float* gB = desc + (size_t)(col0 + rr) * D + k0 + (sc << 3);
        const float4 fb0 = *reinterpret_cast<const float4*>(gB);
        const float4 fb1 = *reinterpret_cast<const float4*>(gB + 4);
        uint4 wa, wb;
        wa.x = pack_bf16x2(fa0.x, fa0.y);
        wa.y = pack_bf16x2(fa0.z, fa0.w);
        wa.z = pack_bf16x2(fa1.x, fa1.y);
        wa.w = pack_bf16x2(fa1.z, fa1.w);
        wb.x = pack_bf16x2(fb0.x, fb0.y);
        wb.y = pack_bf16x2(fb0.z, fb0.w);
        wb.z = pack_bf16x2(fb1.x, fb1.y);
        wb.w = pack_bf16x2(fb1.z, fb1.w);
        const int dst = (sc ^ (rr & 7)) << 3;
        *reinterpret_cast<uint4*>(&lA[0][rr][dst]) = wa;
        *reinterpret_cast<uint4*>(&lB[0][rr][dst]) = wb;
      }
      __syncthreads();
#pragma unroll
      for (int kk = 0; kk < 2; ++kk) {
        short8v af[4], bf[4];
#pragma unroll
        for (int m = 0; m < 4; ++m) {
          const int rowa = wrow + (m << 4) + lr;
          const int ch = ((kk << 2) + kg) ^ (rowa & 7);
          af[m] = *reinterpret_cast<const short8v*>(&lA[0][rowa][ch << 3]);
        }
#pragma unroll
        for (int n = 0; n < 4; ++n) {
          const int rowb = wcol + (n << 4) + lr;
          const int ch = ((kk << 2) + kg) ^ (rowb & 7);
          bf[n] = *reinterpret_cast<const short8v*>(&lB[0][rowb][ch << 3]);
        }
#pragma unroll
        for (int m = 0; m < 4; ++m)
#pragma unroll
          for (int n = 0; n < 4; ++n)
            acc[m][n] = __builtin_amdgcn_mfma_f32_16x16x32_bf16(af[m], bf[n],
                                                                acc[m][n], 0, 0, 0);
      }
    }
    __syncthreads();
  }

  // LDS reuse for MODE=2 cross-wave combine (lA/lB are dead after K-loop).
  float* rowred = (float*)&lA[0][0][0];  // [2][TILE][3]
  float* colred = (float*)&lB[0][0][0];  // [2][TILE][3]

  // ---- epilogue: per-row (and per-col if upper) partial sums ----
  int cseq[4], ctim[4], gcol[4];
#pragma unroll
  for (int n = 0; n < 4; ++n) {
    const int cl = wcol + (n << 4) + lr;
    cseq[n] = mseq_c[cl];
    ctim[n] = mtim_c[cl];
    gcol[n] = col0 + cl;
  }
  float colse[4] = {0.f, 0.f, 0.f, 0.f};
  float colpd[4] = {0.f, 0.f, 0.f, 0.f};
  float colpc[4] = {0.f, 0.f, 0.f, 0.f};

#pragma unroll
  for (int m = 0; m < 4; ++m) {
#pragma unroll
    for (int reg = 0; reg < 4; ++reg) {
      const int rl = wrow + (m << 4) + (kg << 2) + reg;  // row within tile
      const int growg = row0 + rl;
      const int rs = mseq_r[rl];
      const int rt = mtim_r[rl];
      float se = 0.f, pd = 0.f, pcnt = 0.f;
#pragma unroll
      for (int n = 0; n < 4; ++n) {
        const float dot = acc[m][n][reg];
        const float e = exp2f(fmaf(dot, K2C, -K2C));
        const bool nd = (growg != gcol[n]);
        int dt = rt - ctim[n];
        dt = dt < 0 ? -dt : dt;
        const bool pos = nd && (rs == cseq[n]) && (dt < TIME_THR);
        const float ev = nd ? e : 0.f;
        const float dv = pos ? dot : 0.f;
        const float cv = pos ? 1.f : 0.f;
        se += ev;
        pd += dv;
        pcnt += cv;
        if (upper) {
          colse[n] += ev;
          colpd[n] += dv;
          colpc[n] += cv;
        }
      }
      // reduce across the 16 lanes that share this row
#pragma unroll
      for (int s = 1; s < 16; s <<= 1) {
        se += __shfl_xor(se, s);
        pd += __shfl_xor(pd, s);
        pcnt += __shfl_xor(pcnt, s);
      }
      if ((l & 15) == 0) {
        if (MODE == 2) {
          const int half = wcol >> 6;
          float* rr3 = rowred + ((size_t)(half * TILE + rl)) * 3;
          rr3[0] = se;
          rr3[1] = pd;
          rr3[2] = pcnt;
        } else {
          atomicAdd(&p_se[growg], se);
          atomicAdd(&p_ps[growg], pd * INV_T);
          atomicAdd(&p_pc[growg], pcnt);
        }
      }
    }
  }
  if (upper) {
    // column sums = row sums of the mirrored (transposed) tile
#pragma unroll
    for (int n = 0; n < 4; ++n) {
      float cs = colse[n], cp = colpd[n], cc = colpc[n];
      cs += __shfl_xor(cs, 16);
      cp += __shfl_xor(cp, 16);
      cc += __shfl_xor(cc, 16);
      cs += __shfl_xor(cs, 32);
      cp += __shfl_xor(cp, 32);
      cc += __shfl_xor(cc, 32);
      if (kg == 0) {
        if (MODE == 2) {
          const int half = wrow >> 6;
          const int cl = wcol + (n << 4) + lr;
          float* cr3 = colred + ((size_t)(half * TILE + cl)) * 3;
          cr3[0] = cs;
          cr3[1] = cp;
          cr3[2] = cc;
        } else {
          atomicAdd(&p_se[gcol[n]], cs);
          atomicAdd(&p_ps[gcol[n]], cp * INV_T);
          atomicAdd(&p_pc[gcol[n]], cc);
        }
      }
    }
  }

  if (MODE == 2) {
    __syncthreads();  // rowred/colred complete
    if (tid < TILE) {
      const int row = tid;
      const float se = rowred[(size_t)row * 3 + 0] + rowred[(size_t)(TILE + row) * 3 + 0];
      const float pd = rowred[(size_t)row * 3 + 1] + rowred[(size_t)(TILE + row) * 3 + 1];
      const float pc = rowred[(size_t)row * 3 + 2] + rowred[(size_t)(TILE + row) * 3 + 2];
      const size_t o = (size_t)cb * B + row0 + row;  // slot-major, coalesced
      p_se[o] = se;
      p_ps[o] = pd * INV_T;
      p_pc[o] = pc;
    } else if (upper && tid < 2 * TILE) {
      const int col = tid - TILE;
      const float se = colred[(size_t)col * 3 + 0] + colred[(size_t)(TILE + col) * 3 + 0];
      const float pd = colred[(size_t)col * 3 + 1] + colred[(size_t)(TILE + col) * 3 + 1];
      const float pc = colred[(size_t)col * 3 + 2] + colred[(size_t)(TILE + col) * 3 + 2];
      const size_t o = (size_t)rb * B + col0 + col;  // slot-major, coalesced
      p_se[o] = se;
      p_ps[o] = pd * INV_T;
      p_pc[o] = pc;
    }
  }
}

__global__ __launch_bounds__(256, 2) void infonce_main2(
    const float* desc, const unsigned short* descb, const int* seq,
    const int* tmid, float* p_se, float* p_ps, float* p_pc, int B, int D,
    int NB) {
  infonce_body<2>(desc, descb, seq, tmid, p_se, p_ps, p_pc, B, D, NB);
}
__global__ __launch_bounds__(256, 2) void infonce_main1(
    const float* desc, const unsigned short* descb, const int* seq,
    const int* tmid, float* p_se, float* p_ps, float* p_pc, int B, int D,
    int NB) {
  infonce_body<1>(desc, descb, seq, tmid, p_se, p_ps, p_pc, B, D, NB);
}
__global__ __launch_bounds__(256, 2) void infonce_main0(
    const float* desc, const unsigned short* descb, const int* seq,
    const int* tmid, float* p_se, float* p_ps, float* p_pc, int B, int D,
    int NB) {
  infonce_body<0>(desc, descb, seq, tmid, p_se, p_ps, p_pc, B, D, NB);
}

__global__ __launch_bounds__(256) void conv_bf16(const float* __restrict__ in,
                                                 unsigned short* __restrict__ out,
                                                 int n8) {
  const int i = blockIdx.x * 256 + threadIdx.x;
  if (i >= n8) return;
  const float4 f0 = *reinterpret_cast<const float4*>(in + (size_t)i * 8);
  const float4 f1 = *reinterpret_cast<const float4*>(in + (size_t)i * 8 + 4);
  uint4 wv;
  wv.x = pack_bf16x2(f0.x, f0.y);
  wv.y = pack_bf16x2(f0.z, f0.w);
  wv.z = pack_bf16x2(f1.x, f1.y);
  wv.w = pack_bf16x2(f1.z, f1.w);
  *reinterpret_cast<uint4*>(out + (size_t)i * 8) = wv;
}

// 4 threads per row (NB quarters), 64 rows/block -> B/64 blocks.
__global__ __launch_bounds__(256) void reduce_parts4(
    const float* __restrict__ p_se, const float* __restrict__ p_ps,
    const float* __restrict__ p_pc, float* __restrict__ bnum,
    float* __restrict__ bcnt, int B, int NB) {
  const int tid = threadIdx.x;
  const int rloc = tid & 63;
  const int chunk = tid >> 6;  // 0..3
  const int row = blockIdx.x * 64 + rloc;
  const int jpc = NB >> 2;
  float se = 0.f, ps = 0.f, pc = 0.f;
  for (int j = chunk * jpc; j < (chunk + 1) * jpc; ++j) {
    const size_t o = (size_t)j * B + row;
    se += p_se[o];
    ps += p_ps[o];
    pc += p_pc[o];
  }
  __shared__ float s3[3][4][64];
  s3[0][chunk][rloc] = se;
  s3[1][chunk][rloc] = ps;
  s3[2][chunk][rloc] = pc;
  __syncthreads();
  if (tid < 64) {
    const float tse = s3[0][0][tid] + s3[0][1][tid] + s3[0][2][tid] + s3[0][3][tid];
    const float tps = s3[1][0][tid] + s3[1][1][tid] + s3[1][2][tid] + s3[1][3][tid];
    const float tpc = s3[2][0][tid] + s3[2][1][tid] + s3[2][2][tid] + s3[2][3][tid];
    float a = tpc * (logf(tse) + INV_T) - tps;
    float b = tpc;
#pragma unroll
    for (int s = 1; s < 64; s <<= 1) {
      a += __shfl_xor(a, s);
      b += __shfl_xor(b, s);
    }
    if (tid == 0) {
      bnum[blockIdx.x] = a;
      bcnt[blockIdx.x] = b;
    }
  }
}

// fallback: one thread per row; slot-major parts -> coalesced loads.
__global__ __launch_bounds__(256) void reduce_parts(
    const float* __restrict__ p_se, const float* __restrict__ p_ps,
    const float* __restrict__ p_pc, float* __restrict__ bnum,
    float* __restrict__ bcnt, int B, int NB) {
  const int tid = threadIdx.x;
  const int row = blockIdx.x * 256 + tid;
  float se = 0.f, ps = 0.f, pc = 0.f;
  for (int j = 0; j < NB; ++j) {
    const size_t o = (size_t)j * B + row;
    se += p_se[o];
    ps += p_ps[o];
    pc += p_pc[o];
  }
  float num = pc * (logf(se) + INV_T) - ps;
  __shared__ float sn[256];
  __shared__ float sc[256];
  sn[tid] = num;
  sc[tid] = pc;
  __syncthreads();
  for (int s = 128; s > 0; s >>= 1) {
    if (tid < s) {
      sn[tid] += sn[tid + s];
      sc[tid] += sc[tid + s];
    }
    __syncthreads();
  }
  if (tid == 0) {
    bnum[blockIdx.x] = sn[0];
    bcnt[blockIdx.x] = sc[0];
  }
}

__global__ __launch_bounds__(256) void final_reduce(
    const float* __restrict__ bnum, const float* __restrict__ bcnt,
    float* __restrict__ out, int n) {
  __shared__ float sn[256];
  __shared__ float sc[256];
  const int tid = threadIdx.x;
  float a = 0.f, b = 0.f;
  for (int i = tid; i < n; i += 256) {
    a += bnum[i];
    b += bcnt[i];
  }
  sn[tid] = a;
  sc[tid] = b;
  __syncthreads();
  for (int s = 128; s > 0; s >>= 1) {
    if (tid < s) {
      sn[tid] += sn[tid + s];
      sc[tid] += sc[tid + s];
    }
    __syncthreads();
  }
  if (tid == 0) out[0] = sn[0] / fmaxf(sc[0], 1.f);
}

// fallback finalize for atomic modes (reads flat a_se/a_ps/a_pc)
__global__ __launch_bounds__(1024) void infonce_finalize(
    const float* __restrict__ a_se, const float* __restrict__ a_ps,
    const float* __restrict__ a_pc, float* __restrict__ out, int B) {
  __shared__ float sn[1024];
  __shared__ float sc[1024];
  const int tid = threadIdx.x;
  float num = 0.f, cnt = 0.f;
  for (int i = tid; i < B; i += 1024) {
    const float c = a_pc[i];
    num += c * (logf(a_se[i]) + INV_T) - a_ps[i];
    cnt += c;
  }
  sn[tid] = num;
  sc[tid] = cnt;
  __syncthreads();
  for (int s = 512; s > 0; s >>= 1) {
    if (tid < s) {
      sn[tid] += sn[tid + s];
      sc[tid] += sc[tid + s];
    }
    __syncthreads();
  }
  if (tid == 0) out[0] = sn[0] / fmaxf(sc[0], 1.f);
}

extern "C" void kernel_launch(void* const* d_in, const int* in_sizes, int n_in,
                              void* d_out, int out_size, void* d_ws, size_t ws_size,
                              hipStream_t stream) {
  (void)n_in;
  (void)out_size;
  const float* desc = (const float*)d_in[0];
  const int* seq = (const int*)d_in[1];
  const int* tmid = (const int*)d_in[2];
  const int B = in_sizes[1];
  const int D = in_sizes[0] / B;
  const int NB = B / TILE;
  const int T = NB * (NB + 1) / 2;
  const int n8 = B * D / 8;

  const size_t descb_bytes = (size_t)B * D * 2;
  const size_t parts_elems = (size_t)B * NB;
  const size_t nb1 = (size_t)B / 64;  // reduce_parts4 blocks (max case)
  const size_t need2 = descb_bytes + 3 * parts_elems * 4 + 2 * nb1 * 4;
  const size_t need1 = (size_t)3 * B * 4 + descb_bytes;

  if ((B & 255) == 0 && (D & 63) == 0 && ws_size >= need2) {
    // MODE 2: atomic-free
    unsigned short* descb = (unsigned short*)d_ws;
    float* p_se = (float*)((char*)d_ws + descb_bytes);
    float* p_ps = p_se + parts_elems;
    float* p_pc = p_ps + parts_elems;
    float* bnum = p_pc + parts_elems;
    float* bcnt = bnum + nb1;
    conv_bf16<<<(n8 + 255) / 256, 256, 0, stream>>>(desc, descb, n8);
    infonce_main2<<<T, 256, 0, stream>>>(desc, descb, seq, tmid, p_se, p_ps,
                                         p_pc, B, D, NB);
    if ((NB & 3) == 0 && (B & 63) == 0) {
      const int nrb = B / 64;
      reduce_parts4<<<nrb, 256, 0, stream>>>(p_se, p_ps, p_pc, bnum, bcnt, B, NB);
      final_reduce<<<1, 256, 0, stream>>>(bnum, bcnt, (float*)d_out, nrb);
    } else {
      const int nrb = B / 256;
      reduce_parts<<<nrb, 256, 0, stream>>>(p_se, p_ps, p_pc, bnum, bcnt, B, NB);
      final_reduce<<<1, 256, 0, stream>>>(bnum, bcnt, (float*)d_out, nrb);
    }
  } else if (ws_size >= need1) {
    float* a_se = (float*)d_ws;
    float* a_ps = a_se + B;
    float* a_pc = a_ps + B;
    unsigned short* descb = (unsigned short*)((char*)d_ws + (size_t)3 * B * 4);
    hipMemsetAsync(d_ws, 0, (size_t)3 * B * sizeof(float), stream);
    conv_bf16<<<(n8 + 255) / 256, 256, 0, stream>>>(desc, descb, n8);
    infonce_main1<<<T, 256, 0, stream>>>(desc, descb, seq, tmid, a_se, a_ps,
                                         a_pc, B, D, NB);
    infonce_finalize<<<1, 1024, 0, stream>>>(a_se, a_ps, a_pc, (float*)d_out, B);
  } else {
    float* a_se = (float*)d_ws;
    float* a_ps = a_se + B;
    float* a_pc = a_ps + B;
    hipMemsetAsync(d_ws, 0, (size_t)3 * B * sizeof(float), stream);
    infonce_main0<<<T, 256, 0, stream>>>(desc, nullptr, seq, tmid, a_se, a_ps,
                                         a_pc, B, D, NB);
    infonce_finalize<<<1, 1024, 0, stream>>>(a_se, a_ps, a_pc, (float*)d_out, B);
  }
}